// Round 1
// baseline (1268.227 us; speedup 1.0000x reference)
//
#include <hip/hip_runtime.h>
#include <hip/hip_bf16.h>

#define NN 10000
#define EE 320000
#define DD 256
#define LL 5

// ---------------- CSR build ----------------

__global__ void zero_deg_k(int* __restrict__ deg) {
    int i = blockIdx.x * blockDim.x + threadIdx.x;
    if (i < NN) deg[i] = 0;
}

__global__ void hist_k(const int* __restrict__ dst, int* __restrict__ deg) {
    int e = blockIdx.x * blockDim.x + threadIdx.x;
    if (e < EE) atomicAdd(&deg[dst[e]], 1);
}

// single-block exclusive scan over deg[0..NN) -> row_start, cursor
__global__ void scan_k(const int* __restrict__ deg, int* __restrict__ row_start,
                       int* __restrict__ cursor) {
    __shared__ int sums[1024];
    const int CH = 10;  // 1024*10 >= 10000
    int t = threadIdx.x;
    int base = t * CH;
    int loc[CH];
    int s = 0;
#pragma unroll
    for (int i = 0; i < CH; i++) {
        int v = (base + i < NN) ? deg[base + i] : 0;
        loc[i] = s;
        s += v;
    }
    sums[t] = s;
    __syncthreads();
    for (int off = 1; off < 1024; off <<= 1) {
        int v = (t >= off) ? sums[t - off] : 0;
        __syncthreads();
        sums[t] += v;
        __syncthreads();
    }
    int pre = (t == 0) ? 0 : sums[t - 1];
#pragma unroll
    for (int i = 0; i < CH; i++) {
        int idx = base + i;
        if (idx < NN) {
            int v = pre + loc[i];
            row_start[idx] = v;
            cursor[idx] = v;
        }
    }
    if (t == 1023) row_start[NN] = sums[1023];
}

__global__ void fill_k(const int* __restrict__ ei, const float* __restrict__ attr,
                       int* __restrict__ cursor, int* __restrict__ ssrc,
                       float* __restrict__ sattr) {
    int e = blockIdx.x * blockDim.x + threadIdx.x;
    if (e < EE) {
        int dv = ei[EE + e];
        int p = atomicAdd(&cursor[dv], 1);
        ssrc[p] = ei[e];
        sattr[p] = attr[e];
    }
}

// ---------------- weight transpose: Wt[l][j][k] = W[l][k][j] ----------------

__global__ void transpose_w_k(const float* __restrict__ W, float* __restrict__ Wt) {
    __shared__ float t[32][33];
    int l = blockIdx.z;
    int bx = blockIdx.x * 32;  // k tile in source cols
    int by = blockIdx.y * 32;  // row tile in source rows
    for (int i = threadIdx.y; i < 32; i += 8)
        t[i][threadIdx.x] = W[l * 65536 + (by + i) * DD + bx + threadIdx.x];
    __syncthreads();
    for (int i = threadIdx.y; i < 32; i += 8)
        Wt[l * 65536 + (bx + i) * DD + by + threadIdx.x] = t[threadIdx.x][i];
}

// ---------------- m = h @ W  (NT form: C[n,j] = sum_k A[n,k]*B[j,k]) ----------------

__global__ __launch_bounds__(256)
void gemm_nt64_k(const float* __restrict__ A, const float* __restrict__ B,
                 float* __restrict__ C) {
    __shared__ float As[16][68];
    __shared__ float Bs[16][68];
    int tid = threadIdx.x;
    int tx = tid & 15, ty = tid >> 4;
    int rowBase = blockIdx.x * 64;
    int colBase = blockIdx.y * 64;
    int lr = tid >> 2, lq = tid & 3;
    float acc[4][4];
#pragma unroll
    for (int i = 0; i < 4; i++)
#pragma unroll
        for (int j = 0; j < 4; j++) acc[i][j] = 0.f;

    for (int k0 = 0; k0 < 256; k0 += 16) {
        float4 av = make_float4(0.f, 0.f, 0.f, 0.f);
        int arow = rowBase + lr;
        if (arow < NN) av = *(const float4*)(A + arow * DD + k0 + lq * 4);
        float4 bv = *(const float4*)(B + (colBase + lr) * DD + k0 + lq * 4);
        __syncthreads();
        As[lq * 4 + 0][lr] = av.x; As[lq * 4 + 1][lr] = av.y;
        As[lq * 4 + 2][lr] = av.z; As[lq * 4 + 3][lr] = av.w;
        Bs[lq * 4 + 0][lr] = bv.x; Bs[lq * 4 + 1][lr] = bv.y;
        Bs[lq * 4 + 2][lr] = bv.z; Bs[lq * 4 + 3][lr] = bv.w;
        __syncthreads();
#pragma unroll
        for (int kk = 0; kk < 16; kk++) {
            float a0 = As[kk][ty * 4 + 0], a1 = As[kk][ty * 4 + 1];
            float a2 = As[kk][ty * 4 + 2], a3 = As[kk][ty * 4 + 3];
            float b0 = Bs[kk][tx * 4 + 0], b1 = Bs[kk][tx * 4 + 1];
            float b2 = Bs[kk][tx * 4 + 2], b3 = Bs[kk][tx * 4 + 3];
            acc[0][0] += a0 * b0; acc[0][1] += a0 * b1; acc[0][2] += a0 * b2; acc[0][3] += a0 * b3;
            acc[1][0] += a1 * b0; acc[1][1] += a1 * b1; acc[1][2] += a1 * b2; acc[1][3] += a1 * b3;
            acc[2][0] += a2 * b0; acc[2][1] += a2 * b1; acc[2][2] += a2 * b2; acc[2][3] += a2 * b3;
            acc[3][0] += a3 * b0; acc[3][1] += a3 * b1; acc[3][2] += a3 * b2; acc[3][3] += a3 * b3;
        }
    }
#pragma unroll
    for (int i = 0; i < 4; i++) {
        int arow = rowBase + ty * 4 + i;
        if (arow < NN) {
            *(float4*)(C + arow * DD + colBase + tx * 4) =
                make_float4(acc[i][0], acc[i][1], acc[i][2], acc[i][3]);
        }
    }
}

// ---------------- aggregation: agg[n,:] = sum_{e: dst=n} m[src_e,:]*attr_e ----------------

__global__ __launch_bounds__(256)
void aggregate_k(const float* __restrict__ m, const int* __restrict__ row_start,
                 const int* __restrict__ ssrc, const float* __restrict__ sattr,
                 float* __restrict__ agg) {
    int n = blockIdx.x;
    int d = threadIdx.x;
    int s0 = row_start[n], s1 = row_start[n + 1];
    float a0 = 0.f, a1 = 0.f, a2 = 0.f, a3 = 0.f;
    int i = s0;
    for (; i + 3 < s1; i += 4) {
        int sA = ssrc[i + 0], sB = ssrc[i + 1], sC = ssrc[i + 2], sD = ssrc[i + 3];
        float wA = sattr[i + 0], wB = sattr[i + 1], wC = sattr[i + 2], wD = sattr[i + 3];
        a0 += m[sA * DD + d] * wA;
        a1 += m[sB * DD + d] * wB;
        a2 += m[sC * DD + d] * wC;
        a3 += m[sD * DD + d] * wD;
    }
    for (; i < s1; i++) {
        a0 += m[ssrc[i] * DD + d] * sattr[i];
    }
    agg[n * DD + d] = (a0 + a1) + (a2 + a3);
}

// ---------------- fused GRU: 6 gate GEMMs + gate math ----------------
// block: 32 nodes x 64 feature-cols; thread tile 2 nodes x 4 cols; 48 accumulators

__global__ __launch_bounds__(256)
void gru_fused_k(const float* __restrict__ agg, const float* __restrict__ hin,
                 const float* __restrict__ w_ih, const float* __restrict__ w_hh,
                 const float* __restrict__ b_ih, const float* __restrict__ b_hh,
                 float* __restrict__ hout) {
    __shared__ float Aagg[16][34];
    __shared__ float Ah[16][34];
    __shared__ float Ws[6][16][64];
    int tid = threadIdx.x;
    int tx = tid & 15;
    int ty = tid >> 4;
    int nodeBase = blockIdx.x * 32;
    int colBase = blockIdx.y * 64;
    float acc[6][2][4];
#pragma unroll
    for (int g = 0; g < 6; g++)
#pragma unroll
        for (int i = 0; i < 2; i++)
#pragma unroll
            for (int j = 0; j < 4; j++) acc[g][i][j] = 0.f;

    int ar = (tid & 127) >> 2;  // 0..31
    int aq = tid & 3;
    bool loadH = (tid >= 128);
    int wr = tid >> 2;  // 0..63
    int wq = tid & 3;

    for (int k0 = 0; k0 < 256; k0 += 16) {
        int arow = nodeBase + ar;
        const float* Ab = loadH ? hin : agg;
        float4 av = make_float4(0.f, 0.f, 0.f, 0.f);
        if (arow < NN) av = *(const float4*)(Ab + arow * DD + k0 + aq * 4);
        float4 wv[6];
#pragma unroll
        for (int g = 0; g < 6; g++) {
            const float* Wb = (g < 3) ? w_ih : w_hh;
            int grow = colBase + wr + (g % 3) * 256;
            wv[g] = *(const float4*)(Wb + grow * DD + k0 + wq * 4);
        }
        __syncthreads();
        if (loadH) {
            Ah[aq * 4 + 0][ar] = av.x; Ah[aq * 4 + 1][ar] = av.y;
            Ah[aq * 4 + 2][ar] = av.z; Ah[aq * 4 + 3][ar] = av.w;
        } else {
            Aagg[aq * 4 + 0][ar] = av.x; Aagg[aq * 4 + 1][ar] = av.y;
            Aagg[aq * 4 + 2][ar] = av.z; Aagg[aq * 4 + 3][ar] = av.w;
        }
#pragma unroll
        for (int g = 0; g < 6; g++) {
            Ws[g][wq * 4 + 0][wr] = wv[g].x; Ws[g][wq * 4 + 1][wr] = wv[g].y;
            Ws[g][wq * 4 + 2][wr] = wv[g].z; Ws[g][wq * 4 + 3][wr] = wv[g].w;
        }
        __syncthreads();
#pragma unroll
        for (int kk = 0; kk < 16; kk++) {
            float aa0 = Aagg[kk][ty * 2 + 0], aa1 = Aagg[kk][ty * 2 + 1];
            float ah0 = Ah[kk][ty * 2 + 0], ah1 = Ah[kk][ty * 2 + 1];
#pragma unroll
            for (int g = 0; g < 6; g++) {
                float4 w4 = *(const float4*)&Ws[g][kk][tx * 4];
                float a0 = (g < 3) ? aa0 : ah0;
                float a1 = (g < 3) ? aa1 : ah1;
                acc[g][0][0] += a0 * w4.x; acc[g][0][1] += a0 * w4.y;
                acc[g][0][2] += a0 * w4.z; acc[g][0][3] += a0 * w4.w;
                acc[g][1][0] += a1 * w4.x; acc[g][1][1] += a1 * w4.y;
                acc[g][1][2] += a1 * w4.z; acc[g][1][3] += a1 * w4.w;
            }
        }
    }
#pragma unroll
    for (int i = 0; i < 2; i++) {
        int n = nodeBase + ty * 2 + i;
        if (n >= NN) continue;
#pragma unroll
        for (int j = 0; j < 4; j++) {
            int d = colBase + tx * 4 + j;
            float ir = acc[0][i][j] + b_ih[d];
            float iz = acc[1][i][j] + b_ih[d + 256];
            float in_ = acc[2][i][j] + b_ih[d + 512];
            float hr = acc[3][i][j] + b_hh[d];
            float hz = acc[4][i][j] + b_hh[d + 256];
            float hn = acc[5][i][j] + b_hh[d + 512];
            float r = 1.f / (1.f + __expf(-(ir + hr)));
            float z = 1.f / (1.f + __expf(-(iz + hz)));
            float nn = tanhf(in_ + r * hn);
            float hp = hin[n * DD + d];
            hout[n * DD + d] = (1.f - z) * nn + z * hp;
        }
    }
}

// ---------------- launch ----------------

extern "C" void kernel_launch(void* const* d_in, const int* in_sizes, int n_in,
                              void* d_out, int out_size, void* d_ws, size_t ws_size,
                              hipStream_t stream) {
    const float* x = (const float*)d_in[0];
    const int* edge_index = (const int*)d_in[1];   // [2, E]: row0=src, row1=dst
    const float* edge_attr = (const float*)d_in[2];
    const float* weight = (const float*)d_in[3];   // [L, D, D]
    const float* w_ih = (const float*)d_in[4];     // [3D, D]
    const float* w_hh = (const float*)d_in[5];
    const float* b_ih = (const float*)d_in[6];
    const float* b_hh = (const float*)d_in[7];

    // workspace carve (aligned 256B)
    size_t off = 0;
    char* base = (char*)d_ws;
    auto carve = [&](size_t bytes) -> void* {
        void* p = base + off;
        off += (bytes + 255) & ~(size_t)255;
        return p;
    };
    float* hb = (float*)carve((size_t)NN * DD * 4);
    float* m = (float*)carve((size_t)NN * DD * 4);
    float* agg = (float*)carve((size_t)NN * DD * 4);
    float* Wt = (float*)carve((size_t)LL * DD * DD * 4);
    int* deg = (int*)carve((size_t)NN * 4);
    int* row_start = (int*)carve((size_t)(NN + 1) * 4);
    int* cursor = (int*)carve((size_t)NN * 4);
    int* ssrc = (int*)carve((size_t)EE * 4);
    float* sattr = (float*)carve((size_t)EE * 4);
    (void)ws_size;

    // h0 = x
    hipMemcpyAsync(hb, x, (size_t)NN * DD * 4, hipMemcpyDeviceToDevice, stream);

    // Wt[l][j][k] = W[l][k][j]
    transpose_w_k<<<dim3(8, 8, LL), dim3(32, 8), 0, stream>>>(weight, Wt);

    // CSR by dst (built once per launch, reused across layers)
    zero_deg_k<<<(NN + 255) / 256, 256, 0, stream>>>(deg);
    hist_k<<<(EE + 255) / 256, 256, 0, stream>>>(edge_index + EE, deg);
    scan_k<<<1, 1024, 0, stream>>>(deg, row_start, cursor);
    fill_k<<<(EE + 255) / 256, 256, 0, stream>>>(edge_index, edge_attr, cursor, ssrc, sattr);

    float* hA = hb;
    float* hB = (float*)d_out;
    for (int l = 0; l < LL; l++) {
        gemm_nt64_k<<<dim3(157, 4), 256, 0, stream>>>(hA, Wt + (size_t)l * DD * DD, m);
        aggregate_k<<<NN, 256, 0, stream>>>(m, row_start, ssrc, sattr, agg);
        gru_fused_k<<<dim3(313, 4), 256, 0, stream>>>(agg, hA, w_ih, w_hh, b_ih, b_hh, hB);
        float* t = hA; hA = hB; hB = t;
    }
    // after 5 swaps the last write landed in d_out (hb->out, out->hb, hb->out, out->hb, hb->out)
}

// Round 2
// 661.734 us; speedup vs baseline: 1.9165x; 1.9165x over previous
//
#include <hip/hip_runtime.h>
#include <hip/hip_bf16.h>

#define NN 10000
#define NPAD 10048   // 157 * 64
#define EE 320000
#define DD 256
#define LL 5

typedef __bf16 bf16x8 __attribute__((ext_vector_type(8)));
typedef __bf16 bf16x4 __attribute__((ext_vector_type(4)));
typedef float f32x4 __attribute__((ext_vector_type(4)));

// ---------------- CSR build ----------------

__global__ void zero_deg_k(int* __restrict__ deg) {
    int i = blockIdx.x * blockDim.x + threadIdx.x;
    if (i < NN) deg[i] = 0;
}

__global__ void hist_k(const int* __restrict__ dst, int* __restrict__ deg) {
    int e = blockIdx.x * blockDim.x + threadIdx.x;
    if (e < EE) atomicAdd(&deg[dst[e]], 1);
}

// single-block exclusive scan over deg[0..NN) -> row_start, cursor
__global__ void scan_k(const int* __restrict__ deg, int* __restrict__ row_start,
                       int* __restrict__ cursor) {
    __shared__ int sums[1024];
    const int CH = 10;  // 1024*10 >= 10000
    int t = threadIdx.x;
    int base = t * CH;
    int loc[CH];
    int s = 0;
#pragma unroll
    for (int i = 0; i < CH; i++) {
        int v = (base + i < NN) ? deg[base + i] : 0;
        loc[i] = s;
        s += v;
    }
    sums[t] = s;
    __syncthreads();
    for (int off = 1; off < 1024; off <<= 1) {
        int v = (t >= off) ? sums[t - off] : 0;
        __syncthreads();
        sums[t] += v;
        __syncthreads();
    }
    int pre = (t == 0) ? 0 : sums[t - 1];
#pragma unroll
    for (int i = 0; i < CH; i++) {
        int idx = base + i;
        if (idx < NN) {
            int v = pre + loc[i];
            row_start[idx] = v;
            cursor[idx] = v;
        }
    }
    if (t == 1023) row_start[NN] = sums[1023];
}

__global__ void fill_k(const int* __restrict__ ei, const float* __restrict__ attr,
                       int* __restrict__ cursor, int* __restrict__ ssrc,
                       float* __restrict__ sattr) {
    int e = blockIdx.x * blockDim.x + threadIdx.x;
    if (e < EE) {
        int dv = ei[EE + e];
        int p = atomicAdd(&cursor[dv], 1);
        ssrc[p] = ei[e];
        sattr[p] = attr[e];
    }
}

// ---------------- weight prep ----------------

// Wtb[l][j][k] = W[l][k][j], bf16 (NT layout for m-GEMM)
__global__ void transpose_wb_k(const float* __restrict__ W, __bf16* __restrict__ Wt) {
    __shared__ float t[32][33];
    int l = blockIdx.z;
    int bx = blockIdx.x * 32;
    int by = blockIdx.y * 32;
    for (int i = threadIdx.y; i < 32; i += 8)
        t[i][threadIdx.x] = W[l * 65536 + (by + i) * DD + bx + threadIdx.x];
    __syncthreads();
    for (int i = threadIdx.y; i < 32; i += 8)
        Wt[l * 65536 + (bx + i) * DD + by + threadIdx.x] = (__bf16)t[threadIdx.x][i];
}

__global__ void conv_gruw_k(const float* __restrict__ w_ih, const float* __restrict__ w_hh,
                            __bf16* __restrict__ wihb, __bf16* __restrict__ whhb) {
    int i = blockIdx.x * blockDim.x + threadIdx.x;
    if (i < 768 * 256) {
        wihb[i] = (__bf16)w_ih[i];
        whhb[i] = (__bf16)w_hh[i];
    }
}

// x -> h fp32 copy + h bf16
__global__ void conv_x_k(const float* __restrict__ x, float* __restrict__ hb,
                         __bf16* __restrict__ hbf) {
    int i = blockIdx.x * blockDim.x + threadIdx.x;
    if (i < NN * DD) {
        float v = x[i];
        hb[i] = v;
        hbf[i] = (__bf16)v;
    }
}

// ---------------- m = h @ W[l]  (MFMA, bf16 in/out) ----------------
// block: 64 nodes x 64 cols, 4 waves in 2x2; wave: 32x32 via 2x2 16x16 frags

__global__ __launch_bounds__(256, 2)
void gemm_m_k(const __bf16* __restrict__ hbf, const __bf16* __restrict__ wt,
              __bf16* __restrict__ mout) {
    int tid = threadIdx.x;
    int wave = tid >> 6, lane = tid & 63;
    int ln = lane & 15, quad = lane >> 4;
    int nodeBase = blockIdx.x * 64 + (wave >> 1) * 32;
    int colBase = blockIdx.y * 64 + (wave & 1) * 32;

    f32x4 acc[2][2] = {};
    const __bf16* aRow = hbf + (size_t)(nodeBase + ln) * DD;

#pragma unroll
    for (int k0 = 0; k0 < DD; k0 += 32) {
        int ko = k0 + quad * 8;
        bf16x8 af[2], bf[2];
#pragma unroll
        for (int i = 0; i < 2; i++)
            af[i] = *(const bf16x8*)(aRow + (size_t)i * 16 * DD + ko);
#pragma unroll
        for (int cc = 0; cc < 2; cc++)
            bf[cc] = *(const bf16x8*)(wt + (size_t)(colBase + cc * 16 + ln) * DD + ko);
#pragma unroll
        for (int nf = 0; nf < 2; nf++)
#pragma unroll
            for (int cc = 0; cc < 2; cc++)
                acc[nf][cc] = __builtin_amdgcn_mfma_f32_16x16x32_bf16(af[nf], bf[cc], acc[nf][cc], 0, 0, 0);
    }
#pragma unroll
    for (int nf = 0; nf < 2; nf++)
#pragma unroll
        for (int r = 0; r < 4; r++) {
            int n = nodeBase + nf * 16 + quad * 4 + r;
#pragma unroll
            for (int cc = 0; cc < 2; cc++) {
                int d = colBase + cc * 16 + ln;
                mout[(size_t)n * DD + d] = (__bf16)acc[nf][cc][r];
            }
        }
}

// ---------------- aggregation: agg[n,:] = sum_{e: dst=n} m[src_e,:]*attr_e ----------------
// one wave per node, 4 cols per lane

__global__ __launch_bounds__(256)
void aggregate_bf_k(const __bf16* __restrict__ m, const int* __restrict__ row_start,
                    const int* __restrict__ ssrc, const float* __restrict__ sattr,
                    __bf16* __restrict__ aggb) {
    int n = blockIdx.x * 4 + (threadIdx.x >> 6);
    int c = (threadIdx.x & 63) * 4;
    int s0 = row_start[n], s1 = row_start[n + 1];
    float a0 = 0.f, a1 = 0.f, a2 = 0.f, a3 = 0.f;
    int i = s0;
    for (; i + 1 < s1; i += 2) {
        int sA = ssrc[i], sB = ssrc[i + 1];
        float wA = sattr[i], wB = sattr[i + 1];
        bf16x4 vA = *(const bf16x4*)(m + (size_t)sA * DD + c);
        bf16x4 vB = *(const bf16x4*)(m + (size_t)sB * DD + c);
        a0 += (float)vA[0] * wA; a1 += (float)vA[1] * wA;
        a2 += (float)vA[2] * wA; a3 += (float)vA[3] * wA;
        a0 += (float)vB[0] * wB; a1 += (float)vB[1] * wB;
        a2 += (float)vB[2] * wB; a3 += (float)vB[3] * wB;
    }
    if (i < s1) {
        int sA = ssrc[i];
        float wA = sattr[i];
        bf16x4 vA = *(const bf16x4*)(m + (size_t)sA * DD + c);
        a0 += (float)vA[0] * wA; a1 += (float)vA[1] * wA;
        a2 += (float)vA[2] * wA; a3 += (float)vA[3] * wA;
    }
    bf16x4 o;
    o[0] = (__bf16)a0; o[1] = (__bf16)a1; o[2] = (__bf16)a2; o[3] = (__bf16)a3;
    *(bf16x4*)(aggb + (size_t)n * DD + c) = o;
}

// ---------------- fused GRU: 6 gate GEMMs (MFMA) + gate math ----------------
// block: 64 nodes x 64 cols, 4 waves 2x2; wave: 32 nodes x 32 cols x 6 gates
// no LDS: A/B frags straight from global (weights are L2-resident)

__global__ __launch_bounds__(256, 2)
void gru_mfma_k(const __bf16* __restrict__ aggb, const __bf16* __restrict__ hbf,
                const float* __restrict__ hin,
                const __bf16* __restrict__ wih, const __bf16* __restrict__ whh,
                const float* __restrict__ b_ih, const float* __restrict__ b_hh,
                float* __restrict__ hout, __bf16* __restrict__ hbfout) {
    int tid = threadIdx.x;
    int wave = tid >> 6, lane = tid & 63;
    int ln = lane & 15, quad = lane >> 4;
    int nodeBase = blockIdx.x * 64 + (wave >> 1) * 32;
    int colBase = blockIdx.y * 64 + (wave & 1) * 32;

    f32x4 acc[6][2][2] = {};  // [gate][nodeFrag][colFrag]

    const __bf16* aRow = aggb + (size_t)(nodeBase + ln) * DD;
    const __bf16* hRow = hbf + (size_t)(nodeBase + ln) * DD;

#pragma unroll
    for (int k0 = 0; k0 < DD; k0 += 32) {
        int ko = k0 + quad * 8;
        bf16x8 aA[2], aH[2];
#pragma unroll
        for (int i = 0; i < 2; i++) {
            aA[i] = *(const bf16x8*)(aRow + (size_t)i * 16 * DD + ko);
            aH[i] = *(const bf16x8*)(hRow + (size_t)i * 16 * DD + ko);
        }
#pragma unroll
        for (int g = 0; g < 3; g++) {
#pragma unroll
            for (int cc = 0; cc < 2; cc++) {
                int brow = g * 256 + colBase + cc * 16 + ln;
                bf16x8 bI = *(const bf16x8*)(wih + (size_t)brow * DD + ko);
                bf16x8 bH = *(const bf16x8*)(whh + (size_t)brow * DD + ko);
#pragma unroll
                for (int nf = 0; nf < 2; nf++) {
                    acc[g][nf][cc] = __builtin_amdgcn_mfma_f32_16x16x32_bf16(aA[nf], bI, acc[g][nf][cc], 0, 0, 0);
                    acc[3 + g][nf][cc] = __builtin_amdgcn_mfma_f32_16x16x32_bf16(aH[nf], bH, acc[3 + g][nf][cc], 0, 0, 0);
                }
            }
        }
    }

    // epilogue: gate math, write h fp32 + h bf16
#pragma unroll
    for (int nf = 0; nf < 2; nf++) {
#pragma unroll
        for (int r = 0; r < 4; r++) {
            int n = nodeBase + nf * 16 + quad * 4 + r;
            if (n >= NN) continue;
#pragma unroll
            for (int cc = 0; cc < 2; cc++) {
                int d = colBase + cc * 16 + ln;
                float ir = acc[0][nf][cc][r] + b_ih[d];
                float iz = acc[1][nf][cc][r] + b_ih[d + 256];
                float in_ = acc[2][nf][cc][r] + b_ih[d + 512];
                float hr = acc[3][nf][cc][r] + b_hh[d];
                float hz = acc[4][nf][cc][r] + b_hh[d + 256];
                float hn = acc[5][nf][cc][r] + b_hh[d + 512];
                float rr = 1.f / (1.f + __expf(-(ir + hr)));
                float zz = 1.f / (1.f + __expf(-(iz + hz)));
                float ax = in_ + rr * hn;
                float e2 = __expf(-2.f * ax);
                float nnv = 2.f / (1.f + e2) - 1.f;  // tanh, no inf/inf
                float hp = hin[(size_t)n * DD + d];
                float o = (1.f - zz) * nnv + zz * hp;
                hout[(size_t)n * DD + d] = o;
                hbfout[(size_t)n * DD + d] = (__bf16)o;
            }
        }
    }
}

// ---------------- launch ----------------

extern "C" void kernel_launch(void* const* d_in, const int* in_sizes, int n_in,
                              void* d_out, int out_size, void* d_ws, size_t ws_size,
                              hipStream_t stream) {
    const float* x = (const float*)d_in[0];
    const int* edge_index = (const int*)d_in[1];   // [2, E]: row0=src, row1=dst
    const float* edge_attr = (const float*)d_in[2];
    const float* weight = (const float*)d_in[3];   // [L, D, D]
    const float* w_ih = (const float*)d_in[4];     // [3D, D]
    const float* w_hh = (const float*)d_in[5];
    const float* b_ih = (const float*)d_in[6];
    const float* b_hh = (const float*)d_in[7];

    size_t off = 0;
    char* base = (char*)d_ws;
    auto carve = [&](size_t bytes) -> void* {
        void* p = base + off;
        off += (bytes + 255) & ~(size_t)255;
        return p;
    };
    float* hb = (float*)carve((size_t)NPAD * DD * 4);
    __bf16* hbfA = (__bf16*)carve((size_t)NPAD * DD * 2);
    __bf16* hbfB = (__bf16*)carve((size_t)NPAD * DD * 2);
    __bf16* mb = (__bf16*)carve((size_t)NPAD * DD * 2);
    __bf16* aggb = (__bf16*)carve((size_t)NPAD * DD * 2);
    __bf16* wtb = (__bf16*)carve((size_t)LL * DD * DD * 2);
    __bf16* wihb = (__bf16*)carve((size_t)768 * DD * 2);
    __bf16* whhb = (__bf16*)carve((size_t)768 * DD * 2);
    int* deg = (int*)carve((size_t)NN * 4);
    int* row_start = (int*)carve((size_t)(NN + 1) * 4);
    int* cursor = (int*)carve((size_t)NN * 4);
    int* ssrc = (int*)carve((size_t)EE * 4);
    float* sattr = (float*)carve((size_t)EE * 4);
    (void)ws_size;

    // weight prep + h0
    transpose_wb_k<<<dim3(8, 8, LL), dim3(32, 8), 0, stream>>>(weight, wtb);
    conv_gruw_k<<<(768 * 256 + 255) / 256, 256, 0, stream>>>(w_ih, w_hh, wihb, whhb);
    conv_x_k<<<(NN * DD + 255) / 256, 256, 0, stream>>>(x, hb, hbfA);

    // CSR by dst (built once per launch)
    zero_deg_k<<<(NN + 255) / 256, 256, 0, stream>>>(deg);
    hist_k<<<(EE + 255) / 256, 256, 0, stream>>>(edge_index + EE, deg);
    scan_k<<<1, 1024, 0, stream>>>(deg, row_start, cursor);
    fill_k<<<(EE + 255) / 256, 256, 0, stream>>>(edge_index, edge_attr, cursor, ssrc, sattr);

    float* hA = hb;
    float* hB = (float*)d_out;
    __bf16* hbfIn = hbfA;
    __bf16* hbfOut = hbfB;
    for (int l = 0; l < LL; l++) {
        gemm_m_k<<<dim3(157, 4), 256, 0, stream>>>(hbfIn, wtb + (size_t)l * DD * DD, mb);
        aggregate_bf_k<<<2500, 256, 0, stream>>>(mb, row_start, ssrc, sattr, aggb);
        gru_mfma_k<<<dim3(157, 4), 256, 0, stream>>>(aggb, hbfIn, hA, wihb, whhb, b_ih, b_hh, hB, hbfOut);
        float* t = hA; hA = hB; hB = t;
        __bf16* tb = hbfIn; hbfIn = hbfOut; hbfOut = tb;
    }
    // 5 swaps: final h landed in d_out
}

// Round 4
// 414.859 us; speedup vs baseline: 3.0570x; 1.5951x over previous
//
#include <hip/hip_runtime.h>
#include <hip/hip_bf16.h>

#define NN 10000
#define NPAD 10048   // 157 * 64
#define EE 320000
#define DD 256
#define LL 5

typedef __bf16 bf16x8 __attribute__((ext_vector_type(8)));
typedef __bf16 bf16x4 __attribute__((ext_vector_type(4)));
typedef float f32x4 __attribute__((ext_vector_type(4)));

__device__ __forceinline__ void gload_lds16(const void* g, void* l) {
    __builtin_amdgcn_global_load_lds(
        (const __attribute__((address_space(1))) void*)g,
        (__attribute__((address_space(3))) void*)l, 16, 0, 0);
}

// ---------------- CSR build ----------------

__global__ void zero_deg_k(int* __restrict__ deg) {
    int i = blockIdx.x * blockDim.x + threadIdx.x;
    if (i < NN) deg[i] = 0;
}

__global__ void hist_k(const int* __restrict__ dst, int* __restrict__ deg) {
    int e = blockIdx.x * blockDim.x + threadIdx.x;
    if (e < EE) atomicAdd(&deg[dst[e]], 1);
}

__global__ void scan_k(const int* __restrict__ deg, int* __restrict__ row_start,
                       int* __restrict__ cursor) {
    __shared__ int sums[1024];
    const int CH = 10;
    int t = threadIdx.x;
    int base = t * CH;
    int loc[CH];
    int s = 0;
#pragma unroll
    for (int i = 0; i < CH; i++) {
        int v = (base + i < NN) ? deg[base + i] : 0;
        loc[i] = s;
        s += v;
    }
    sums[t] = s;
    __syncthreads();
    for (int off = 1; off < 1024; off <<= 1) {
        int v = (t >= off) ? sums[t - off] : 0;
        __syncthreads();
        sums[t] += v;
        __syncthreads();
    }
    int pre = (t == 0) ? 0 : sums[t - 1];
#pragma unroll
    for (int i = 0; i < CH; i++) {
        int idx = base + i;
        if (idx < NN) {
            int v = pre + loc[i];
            row_start[idx] = v;
            cursor[idx] = v;
        }
    }
    if (t == 1023) row_start[NN] = sums[1023];
}

__global__ void fill_k(const int* __restrict__ ei, const float* __restrict__ attr,
                       int* __restrict__ cursor, int* __restrict__ ssrc,
                       float* __restrict__ sattr) {
    int e = blockIdx.x * blockDim.x + threadIdx.x;
    if (e < EE) {
        int dv = ei[EE + e];
        int p = atomicAdd(&cursor[dv], 1);
        ssrc[p] = ei[e];
        sattr[p] = attr[e];
    }
}

// ---------------- weight prep ----------------

// Wt[l][j][k] = W[l][k][j], bf16 (NT layout for m-GEMM)
__global__ void transpose_wb_k(const float* __restrict__ W, __bf16* __restrict__ Wt) {
    __shared__ float t[32][33];
    int l = blockIdx.z;
    int bx = blockIdx.x * 32;
    int by = blockIdx.y * 32;
    for (int i = threadIdx.y; i < 32; i += 8)
        t[i][threadIdx.x] = W[l * 65536 + (by + i) * DD + bx + threadIdx.x];
    __syncthreads();
    for (int i = threadIdx.y; i < 32; i += 8)
        Wt[l * 65536 + (bx + i) * DD + by + threadIdx.x] = (__bf16)t[threadIdx.x][i];
}

__global__ void conv_gruw_k(const float* __restrict__ w_ih, const float* __restrict__ w_hh,
                            __bf16* __restrict__ wihb, __bf16* __restrict__ whhb) {
    int i = blockIdx.x * blockDim.x + threadIdx.x;
    if (i < 768 * 256) {
        wihb[i] = (__bf16)w_ih[i];
        whhb[i] = (__bf16)w_hh[i];
    }
}

__global__ void conv_x_k(const float* __restrict__ x, float* __restrict__ hb,
                         __bf16* __restrict__ hbf) {
    int i = blockIdx.x * blockDim.x + threadIdx.x;
    if (i < NN * DD) {
        float v = x[i];
        hb[i] = v;
        hbf[i] = (__bf16)v;
    }
}

// zero the pad rows [NN, NPAD) of the bf16 h/agg buffers (d_ws is poisoned 0xAA)
__global__ void pad_zero_k(__bf16* __restrict__ a, __bf16* __restrict__ b,
                           __bf16* __restrict__ c, __bf16* __restrict__ d) {
    int i = blockIdx.x * blockDim.x + threadIdx.x;
    if (i < (NPAD - NN) * DD) {
        a[NN * DD + i] = (__bf16)0.f;
        b[NN * DD + i] = (__bf16)0.f;
        c[NN * DD + i] = (__bf16)0.f;
        d[NN * DD + i] = (__bf16)0.f;
    }
}

// ---------------- m = h @ W[l]  (LDS-staged MFMA) ----------------
// block: 64 nodes x 64 cols, 4 waves (2x2); per 32-k chunk stage A 4KB + B 4KB

__global__ __launch_bounds__(256, 2)
void gemm_m_k(const __bf16* __restrict__ hbf, const __bf16* __restrict__ wt,
              __bf16* __restrict__ mout) {
    __shared__ __bf16 sA[64][32];
    __shared__ __bf16 sB[64][32];
    int tid = threadIdx.x;
    int wave = tid >> 6, lane = tid & 63;
    int ln = lane & 15, quad = lane >> 4;
    int rowBlock = blockIdx.x * 64;
    int colBlock = blockIdx.y * 64;
    int rowHalf = (wave >> 1) * 32;
    int colHalf = (wave & 1) * 32;
    int r4 = lane >> 2;
    int kb = (lane & 3) * 8;

    f32x4 acc[2][2] = {};

    for (int k0 = 0; k0 < DD; k0 += 32) {
        __syncthreads();
        // waves 0,1 -> A row-groups; waves 2,3 -> B row-groups; 2 insts each
#pragma unroll
        for (int ii = 0; ii < 2; ii++) {
            int rg = (wave & 1) * 2 + ii;  // 0..3 (16 rows each)
            const __bf16* src;
            __bf16* dst;
            if (wave < 2) {
                src = hbf + (size_t)(rowBlock + rg * 16 + r4) * DD + k0 + kb;
                dst = &sA[rg * 16][0];
            } else {
                src = wt + (size_t)(colBlock + rg * 16 + r4) * DD + k0 + kb;
                dst = &sB[rg * 16][0];
            }
            gload_lds16(src, dst);
        }
        __syncthreads();

        bf16x8 af[2], bf[2];
#pragma unroll
        for (int i = 0; i < 2; i++)
            af[i] = *(const bf16x8*)&sA[rowHalf + i * 16 + ln][quad * 8];
#pragma unroll
        for (int cc = 0; cc < 2; cc++)
            bf[cc] = *(const bf16x8*)&sB[colHalf + cc * 16 + ln][quad * 8];
#pragma unroll
        for (int nf = 0; nf < 2; nf++)
#pragma unroll
            for (int cc = 0; cc < 2; cc++)
                acc[nf][cc] = __builtin_amdgcn_mfma_f32_16x16x32_bf16(af[nf], bf[cc], acc[nf][cc], 0, 0, 0);
    }
#pragma unroll
    for (int nf = 0; nf < 2; nf++)
#pragma unroll
        for (int r = 0; r < 4; r++) {
            int n = rowBlock + rowHalf + nf * 16 + quad * 4 + r;
#pragma unroll
            for (int cc = 0; cc < 2; cc++) {
                int d = colBlock + colHalf + cc * 16 + ln;
                mout[(size_t)n * DD + d] = (__bf16)acc[nf][cc][r];
            }
        }
}

// ---------------- aggregation: agg[n,:] = sum_{e: dst=n} m[src_e,:]*attr_e ----------------
// one wave per node, 4 cols per lane, 4-edge unroll for MLP

__global__ __launch_bounds__(256)
void aggregate_bf_k(const __bf16* __restrict__ m, const int* __restrict__ row_start,
                    const int* __restrict__ ssrc, const float* __restrict__ sattr,
                    __bf16* __restrict__ aggb) {
    int n = blockIdx.x * 4 + (threadIdx.x >> 6);
    int c = (threadIdx.x & 63) * 4;
    int s0 = row_start[n], s1 = row_start[n + 1];
    float a0 = 0.f, a1 = 0.f, a2 = 0.f, a3 = 0.f;
    int i = s0;
    for (; i + 3 < s1; i += 4) {
        int sA = ssrc[i], sB = ssrc[i + 1], sC = ssrc[i + 2], sD = ssrc[i + 3];
        float wA = sattr[i], wB = sattr[i + 1], wC = sattr[i + 2], wD = sattr[i + 3];
        bf16x4 vA = *(const bf16x4*)(m + (size_t)sA * DD + c);
        bf16x4 vB = *(const bf16x4*)(m + (size_t)sB * DD + c);
        bf16x4 vC = *(const bf16x4*)(m + (size_t)sC * DD + c);
        bf16x4 vD = *(const bf16x4*)(m + (size_t)sD * DD + c);
        a0 += (float)vA[0] * wA; a1 += (float)vA[1] * wA;
        a2 += (float)vA[2] * wA; a3 += (float)vA[3] * wA;
        a0 += (float)vB[0] * wB; a1 += (float)vB[1] * wB;
        a2 += (float)vB[2] * wB; a3 += (float)vB[3] * wB;
        a0 += (float)vC[0] * wC; a1 += (float)vC[1] * wC;
        a2 += (float)vC[2] * wC; a3 += (float)vC[3] * wC;
        a0 += (float)vD[0] * wD; a1 += (float)vD[1] * wD;
        a2 += (float)vD[2] * wD; a3 += (float)vD[3] * wD;
    }
    for (; i < s1; i++) {
        int sA = ssrc[i];
        float wA = sattr[i];
        bf16x4 vA = *(const bf16x4*)(m + (size_t)sA * DD + c);
        a0 += (float)vA[0] * wA; a1 += (float)vA[1] * wA;
        a2 += (float)vA[2] * wA; a3 += (float)vA[3] * wA;
    }
    bf16x4 o;
    o[0] = (__bf16)a0; o[1] = (__bf16)a1; o[2] = (__bf16)a2; o[3] = (__bf16)a3;
    *(bf16x4*)(aggb + (size_t)n * DD + c) = o;
}

// ---------------- fused GRU: LDS-staged 6-gate MFMA + gate math ----------------
// block: 64 nodes x 64 d-cols, 4 waves (2x2); wave: 32n x 32d x 6 gates
// K-loop: 8 chunks of 32; per chunk stage A(agg,h) 8KB + B(6 slices) 24KB

__global__ __launch_bounds__(256, 2)
void gru_mfma_k(const __bf16* __restrict__ aggb, const __bf16* __restrict__ hbf,
                const float* __restrict__ hin,
                const __bf16* __restrict__ wih, const __bf16* __restrict__ whh,
                const float* __restrict__ b_ih, const float* __restrict__ b_hh,
                float* __restrict__ hout, __bf16* __restrict__ hbfout) {
    __shared__ __bf16 sA[2][64][32];
    __shared__ __bf16 sB[6][64][32];
    int tid = threadIdx.x;
    int wave = tid >> 6, lane = tid & 63;
    int ln = lane & 15, quad = lane >> 4;
    int nodeBlock = blockIdx.x * 64;
    int colBlock = blockIdx.y * 64;
    int nodeHalf = (wave >> 1) * 32;
    int colHalf = (wave & 1) * 32;
    int r4 = lane >> 2;
    int kb = (lane & 3) * 8;

    f32x4 acc[6][2][2] = {};

    for (int k0 = 0; k0 < DD; k0 += 32) {
        __syncthreads();
#pragma unroll
        for (int ii = 0; ii < 8; ii++) {
            int idx = wave * 8 + ii;
            const __bf16* src;
            __bf16* dst;
            if (idx < 8) {
                int s = idx >> 2;
                int rg = idx & 3;
                const __bf16* A = s ? hbf : aggb;
                src = A + (size_t)(nodeBlock + rg * 16 + r4) * DD + k0 + kb;
                dst = &sA[s][rg * 16][0];
            } else {
                int j = idx - 8;
                int g6 = j >> 2;
                int rg = j & 3;
                const __bf16* B = (g6 < 3) ? wih : whh;
                int brow = (g6 % 3) * 256 + colBlock + rg * 16 + r4;
                src = B + (size_t)brow * DD + k0 + kb;
                dst = &sB[g6][rg * 16][0];
            }
            gload_lds16(src, dst);
        }
        __syncthreads();

        bf16x8 aA[2], aH[2];
#pragma unroll
        for (int nf = 0; nf < 2; nf++) {
            aA[nf] = *(const bf16x8*)&sA[0][nodeHalf + nf * 16 + ln][quad * 8];
            aH[nf] = *(const bf16x8*)&sA[1][nodeHalf + nf * 16 + ln][quad * 8];
        }
#pragma unroll
        for (int g = 0; g < 3; g++) {
#pragma unroll
            for (int cc = 0; cc < 2; cc++) {
                bf16x8 bI = *(const bf16x8*)&sB[g][colHalf + cc * 16 + ln][quad * 8];
                bf16x8 bH = *(const bf16x8*)&sB[3 + g][colHalf + cc * 16 + ln][quad * 8];
#pragma unroll
                for (int nf = 0; nf < 2; nf++) {
                    acc[g][nf][cc] = __builtin_amdgcn_mfma_f32_16x16x32_bf16(aA[nf], bI, acc[g][nf][cc], 0, 0, 0);
                    acc[3 + g][nf][cc] = __builtin_amdgcn_mfma_f32_16x16x32_bf16(aH[nf], bH, acc[3 + g][nf][cc], 0, 0, 0);
                }
            }
        }
    }

    // epilogue
#pragma unroll
    for (int nf = 0; nf < 2; nf++) {
#pragma unroll
        for (int r = 0; r < 4; r++) {
            int n = nodeBlock + nodeHalf + nf * 16 + quad * 4 + r;
            if (n >= NN) continue;
#pragma unroll
            for (int cc = 0; cc < 2; cc++) {
                int d = colBlock + colHalf + cc * 16 + ln;
                float ir = acc[0][nf][cc][r] + b_ih[d];
                float iz = acc[1][nf][cc][r] + b_ih[d + 256];
                float in_ = acc[2][nf][cc][r] + b_ih[d + 512];
                float hr = acc[3][nf][cc][r] + b_hh[d];
                float hz = acc[4][nf][cc][r] + b_hh[d + 256];
                float hn = acc[5][nf][cc][r] + b_hh[d + 512];
                float rr = 1.f / (1.f + __expf(-(ir + hr)));
                float zz = 1.f / (1.f + __expf(-(iz + hz)));
                float ax = in_ + rr * hn;
                float e2 = __expf(-2.f * ax);
                float nnv = 2.f / (1.f + e2) - 1.f;
                float hp = hin[(size_t)n * DD + d];
                float o = (1.f - zz) * nnv + zz * hp;
                hout[(size_t)n * DD + d] = o;
                hbfout[(size_t)n * DD + d] = (__bf16)o;
            }
        }
    }
}

// ---------------- launch ----------------

extern "C" void kernel_launch(void* const* d_in, const int* in_sizes, int n_in,
                              void* d_out, int out_size, void* d_ws, size_t ws_size,
                              hipStream_t stream) {
    const float* x = (const float*)d_in[0];
    const int* edge_index = (const int*)d_in[1];
    const float* edge_attr = (const float*)d_in[2];
    const float* weight = (const float*)d_in[3];
    const float* w_ih = (const float*)d_in[4];
    const float* w_hh = (const float*)d_in[5];
    const float* b_ih = (const float*)d_in[6];
    const float* b_hh = (const float*)d_in[7];

    size_t off = 0;
    char* base = (char*)d_ws;
    auto carve = [&](size_t bytes) -> void* {
        void* p = base + off;
        off += (bytes + 255) & ~(size_t)255;
        return p;
    };
    float* hb = (float*)carve((size_t)NPAD * DD * 4);
    __bf16* hbfA = (__bf16*)carve((size_t)NPAD * DD * 2);
    __bf16* hbfB = (__bf16*)carve((size_t)NPAD * DD * 2);
    __bf16* mb = (__bf16*)carve((size_t)NPAD * DD * 2);
    __bf16* aggb = (__bf16*)carve((size_t)NPAD * DD * 2);
    __bf16* wtb = (__bf16*)carve((size_t)LL * DD * DD * 2);
    __bf16* wihb = (__bf16*)carve((size_t)768 * DD * 2);
    __bf16* whhb = (__bf16*)carve((size_t)768 * DD * 2);
    int* deg = (int*)carve((size_t)NN * 4);
    int* row_start = (int*)carve((size_t)(NN + 1) * 4);
    int* cursor = (int*)carve((size_t)NN * 4);
    int* ssrc = (int*)carve((size_t)EE * 4);
    float* sattr = (float*)carve((size_t)EE * 4);
    (void)ws_size;

    // weight prep + h0 + pad hygiene
    transpose_wb_k<<<dim3(8, 8, LL), dim3(32, 8), 0, stream>>>(weight, wtb);
    conv_gruw_k<<<(768 * 256 + 255) / 256, 256, 0, stream>>>(w_ih, w_hh, wihb, whhb);
    conv_x_k<<<(NN * DD + 255) / 256, 256, 0, stream>>>(x, hb, hbfA);
    pad_zero_k<<<((NPAD - NN) * DD + 255) / 256, 256, 0, stream>>>(hbfA, hbfB, mb, aggb);

    // CSR by dst
    zero_deg_k<<<(NN + 255) / 256, 256, 0, stream>>>(deg);
    hist_k<<<(EE + 255) / 256, 256, 0, stream>>>(edge_index + EE, deg);
    scan_k<<<1, 1024, 0, stream>>>(deg, row_start, cursor);
    fill_k<<<(EE + 255) / 256, 256, 0, stream>>>(edge_index, edge_attr, cursor, ssrc, sattr);

    float* hA = hb;
    float* hB = (float*)d_out;
    __bf16* hbfIn = hbfA;
    __bf16* hbfOut = hbfB;
    for (int l = 0; l < LL; l++) {
        gemm_m_k<<<dim3(157, 4), 256, 0, stream>>>(hbfIn, wtb + (size_t)l * DD * DD, mb);
        aggregate_bf_k<<<2500, 256, 0, stream>>>(mb, row_start, ssrc, sattr, aggb);
        gru_mfma_k<<<dim3(157, 4), 256, 0, stream>>>(aggb, hbfIn, hA, wihb, whhb,
                                                     b_ih, b_hh, hB, hbfOut);
        float* t = hA; hA = hB; hB = t;
        __bf16* tb = hbfIn; hbfIn = hbfOut; hbfOut = tb;
    }
    // 5 swaps: final h landed in d_out
}

// Round 5
// 385.534 us; speedup vs baseline: 3.2895x; 1.0761x over previous
//
#include <hip/hip_runtime.h>
#include <hip/hip_bf16.h>

#define NN 10000
#define NPAD 10048   // 157 * 64
#define EE 320000
#define DD 256
#define LL 5

typedef __bf16 bf16x8 __attribute__((ext_vector_type(8)));
typedef __bf16 bf16x4 __attribute__((ext_vector_type(4)));
typedef float f32x4 __attribute__((ext_vector_type(4)));

__device__ __forceinline__ void gload_lds16(const void* g, void* l) {
    __builtin_amdgcn_global_load_lds(
        (const __attribute__((address_space(1))) void*)g,
        (__attribute__((address_space(3))) void*)l, 16, 0, 0);
}

// ---------------- CSR build ----------------

__global__ void zero_deg_k(int* __restrict__ deg) {
    int i = blockIdx.x * blockDim.x + threadIdx.x;
    if (i < NN) deg[i] = 0;
}

__global__ void hist_k(const int* __restrict__ dst, int* __restrict__ deg) {
    int e = blockIdx.x * blockDim.x + threadIdx.x;
    if (e < EE) atomicAdd(&deg[dst[e]], 1);
}

__global__ void scan_k(const int* __restrict__ deg, int* __restrict__ row_start,
                       int* __restrict__ cursor) {
    __shared__ int sums[1024];
    const int CH = 10;
    int t = threadIdx.x;
    int base = t * CH;
    int loc[CH];
    int s = 0;
#pragma unroll
    for (int i = 0; i < CH; i++) {
        int v = (base + i < NN) ? deg[base + i] : 0;
        loc[i] = s;
        s += v;
    }
    sums[t] = s;
    __syncthreads();
    for (int off = 1; off < 1024; off <<= 1) {
        int v = (t >= off) ? sums[t - off] : 0;
        __syncthreads();
        sums[t] += v;
        __syncthreads();
    }
    int pre = (t == 0) ? 0 : sums[t - 1];
#pragma unroll
    for (int i = 0; i < CH; i++) {
        int idx = base + i;
        if (idx < NN) {
            int v = pre + loc[i];
            row_start[idx] = v;
            cursor[idx] = v;
        }
    }
    if (t == 1023) row_start[NN] = sums[1023];
}

__global__ void fill_k(const int* __restrict__ ei, const float* __restrict__ attr,
                       int* __restrict__ cursor, int* __restrict__ ssrc,
                       float* __restrict__ sattr) {
    int e = blockIdx.x * blockDim.x + threadIdx.x;
    if (e < EE) {
        int dv = ei[EE + e];
        int p = atomicAdd(&cursor[dv], 1);
        ssrc[p] = ei[e];
        sattr[p] = attr[e];
    }
}

// ---------------- weight prep ----------------

// Wt[l][j][k] = W[l][k][j], bf16 (NT layout for m-GEMM)
__global__ void transpose_wb_k(const float* __restrict__ W, __bf16* __restrict__ Wt) {
    __shared__ float t[32][33];
    int l = blockIdx.z;
    int bx = blockIdx.x * 32;
    int by = blockIdx.y * 32;
    for (int i = threadIdx.y; i < 32; i += 8)
        t[i][threadIdx.x] = W[l * 65536 + (by + i) * DD + bx + threadIdx.x];
    __syncthreads();
    for (int i = threadIdx.y; i < 32; i += 8)
        Wt[l * 65536 + (bx + i) * DD + by + threadIdx.x] = (__bf16)t[threadIdx.x][i];
}

__global__ void conv_gruw_k(const float* __restrict__ w_ih, const float* __restrict__ w_hh,
                            __bf16* __restrict__ wihb, __bf16* __restrict__ whhb) {
    int i = blockIdx.x * blockDim.x + threadIdx.x;
    if (i < 768 * 256) {
        wihb[i] = (__bf16)w_ih[i];
        whhb[i] = (__bf16)w_hh[i];
    }
}

__global__ void conv_x_k(const float* __restrict__ x, float* __restrict__ hb,
                         __bf16* __restrict__ hbf) {
    int i = blockIdx.x * blockDim.x + threadIdx.x;
    if (i < NN * DD) {
        float v = x[i];
        hb[i] = v;
        hbf[i] = (__bf16)v;
    }
}

// zero the pad rows [NN, NPAD) of the bf16 h/agg buffers (d_ws is poisoned 0xAA)
__global__ void pad_zero_k(__bf16* __restrict__ a, __bf16* __restrict__ b,
                           __bf16* __restrict__ c, __bf16* __restrict__ d) {
    int i = blockIdx.x * blockDim.x + threadIdx.x;
    if (i < (NPAD - NN) * DD) {
        a[NN * DD + i] = (__bf16)0.f;
        b[NN * DD + i] = (__bf16)0.f;
        c[NN * DD + i] = (__bf16)0.f;
        d[NN * DD + i] = (__bf16)0.f;
    }
}

// ---------------- m = h @ W[l]  (LDS-staged MFMA) ----------------
// block: 64 nodes x 64 cols, 4 waves (2x2); per 32-k chunk stage A 4KB + B 4KB

__global__ __launch_bounds__(256, 2)
void gemm_m_k(const __bf16* __restrict__ hbf, const __bf16* __restrict__ wt,
              __bf16* __restrict__ mout) {
    __shared__ __bf16 sA[64][32];
    __shared__ __bf16 sB[64][32];
    int tid = threadIdx.x;
    int wave = tid >> 6, lane = tid & 63;
    int ln = lane & 15, quad = lane >> 4;
    int rowBlock = blockIdx.x * 64;
    int colBlock = blockIdx.y * 64;
    int rowHalf = (wave >> 1) * 32;
    int colHalf = (wave & 1) * 32;
    int r4 = lane >> 2;
    int kb = (lane & 3) * 8;

    f32x4 acc[2][2] = {};

    for (int k0 = 0; k0 < DD; k0 += 32) {
        __syncthreads();
#pragma unroll
        for (int ii = 0; ii < 2; ii++) {
            int rg = (wave & 1) * 2 + ii;
            const __bf16* src;
            __bf16* dst;
            if (wave < 2) {
                src = hbf + (size_t)(rowBlock + rg * 16 + r4) * DD + k0 + kb;
                dst = &sA[rg * 16][0];
            } else {
                src = wt + (size_t)(colBlock + rg * 16 + r4) * DD + k0 + kb;
                dst = &sB[rg * 16][0];
            }
            gload_lds16(src, dst);
        }
        __syncthreads();

        bf16x8 af[2], bf[2];
#pragma unroll
        for (int i = 0; i < 2; i++)
            af[i] = *(const bf16x8*)&sA[rowHalf + i * 16 + ln][quad * 8];
#pragma unroll
        for (int cc = 0; cc < 2; cc++)
            bf[cc] = *(const bf16x8*)&sB[colHalf + cc * 16 + ln][quad * 8];
#pragma unroll
        for (int nf = 0; nf < 2; nf++)
#pragma unroll
            for (int cc = 0; cc < 2; cc++)
                acc[nf][cc] = __builtin_amdgcn_mfma_f32_16x16x32_bf16(af[nf], bf[cc], acc[nf][cc], 0, 0, 0);
    }
#pragma unroll
    for (int nf = 0; nf < 2; nf++)
#pragma unroll
        for (int r = 0; r < 4; r++) {
            int n = rowBlock + rowHalf + nf * 16 + quad * 4 + r;
#pragma unroll
            for (int cc = 0; cc < 2; cc++) {
                int d = colBlock + colHalf + cc * 16 + ln;
                mout[(size_t)n * DD + d] = (__bf16)acc[nf][cc][r];
            }
        }
}

// ---------------- aggregation: agg[n,:] = sum_{e: dst=n} m[src_e,:]*attr_e ----------------
// wave per node. Stage <=64 edge (idx,attr) into wave-private LDS with one coalesced
// load pair, then gather 2 edges per bf16x8 instr (32 lanes x 16B = one 512B row each),
// 8-edge unroll -> 4 independent dwordx4 gathers in flight. Half-wave partials combined
// with shfl_xor(32).

__global__ __launch_bounds__(256)
void aggregate_bf_k(const __bf16* __restrict__ m, const int* __restrict__ row_start,
                    const int* __restrict__ ssrc, const float* __restrict__ sattr,
                    __bf16* __restrict__ aggb) {
    __shared__ int sIdx[4][64];
    __shared__ float sAtt[4][64];
    int w = threadIdx.x >> 6, lane = threadIdx.x & 63;
    int n = blockIdx.x * 4 + w;
    int s0 = row_start[n], s1 = row_start[n + 1];
    int half = lane >> 5;       // which edge of the pair this half-wave handles
    int c8 = (lane & 31) * 8;   // 8 bf16 cols = 16 B per lane

    float acc[8] = {0.f, 0.f, 0.f, 0.f, 0.f, 0.f, 0.f, 0.f};

    for (int base = s0; base < s1; base += 64) {
        int cnt = min(64, s1 - base);
        if (lane < cnt) {
            sIdx[w][lane] = ssrc[base + lane];
            sAtt[w][lane] = sattr[base + lane];
        }
        // wave-private LDS region: same-wave write->read, compiler inserts lgkmcnt waits
        int t = 0;
        for (; t + 8 <= cnt; t += 8) {
#pragma unroll
            for (int u = 0; u < 4; u++) {
                int e = t + u * 2 + half;
                int s = sIdx[w][e];
                float ww = sAtt[w][e];
                bf16x8 v = *(const bf16x8*)(m + (size_t)s * DD + c8);
#pragma unroll
                for (int i = 0; i < 8; i++) acc[i] += (float)v[i] * ww;
            }
        }
        for (; t + 2 <= cnt; t += 2) {
            int e = t + half;
            int s = sIdx[w][e];
            float ww = sAtt[w][e];
            bf16x8 v = *(const bf16x8*)(m + (size_t)s * DD + c8);
#pragma unroll
            for (int i = 0; i < 8; i++) acc[i] += (float)v[i] * ww;
        }
        if (t < cnt && half == 0) {
            int s = sIdx[w][t];
            float ww = sAtt[w][t];
            bf16x8 v = *(const bf16x8*)(m + (size_t)s * DD + c8);
#pragma unroll
            for (int i = 0; i < 8; i++) acc[i] += (float)v[i] * ww;
        }
    }

#pragma unroll
    for (int i = 0; i < 8; i++) acc[i] += __shfl_xor(acc[i], 32, 64);

    if (half == 0) {
        bf16x8 o;
#pragma unroll
        for (int i = 0; i < 8; i++) o[i] = (__bf16)acc[i];
        *(bf16x8*)(aggb + (size_t)n * DD + c8) = o;
    }
}

// ---------------- fused GRU: LDS-staged 6-gate MFMA + gate math ----------------
// block: 64 nodes x 64 d-cols, 4 waves (2x2); wave: 32n x 32d x 6 gates
// K-loop: 8 chunks of 32; per chunk stage A(agg,h) 8KB + B(6 slices) 24KB

__global__ __launch_bounds__(256, 2)
void gru_mfma_k(const __bf16* __restrict__ aggb, const __bf16* __restrict__ hbf,
                const float* __restrict__ hin,
                const __bf16* __restrict__ wih, const __bf16* __restrict__ whh,
                const float* __restrict__ b_ih, const float* __restrict__ b_hh,
                float* __restrict__ hout, __bf16* __restrict__ hbfout) {
    __shared__ __bf16 sA[2][64][32];
    __shared__ __bf16 sB[6][64][32];
    int tid = threadIdx.x;
    int wave = tid >> 6, lane = tid & 63;
    int ln = lane & 15, quad = lane >> 4;
    int nodeBlock = blockIdx.x * 64;
    int colBlock = blockIdx.y * 64;
    int nodeHalf = (wave >> 1) * 32;
    int colHalf = (wave & 1) * 32;
    int r4 = lane >> 2;
    int kb = (lane & 3) * 8;

    f32x4 acc[6][2][2] = {};

    for (int k0 = 0; k0 < DD; k0 += 32) {
        __syncthreads();
#pragma unroll
        for (int ii = 0; ii < 8; ii++) {
            int idx = wave * 8 + ii;
            const __bf16* src;
            __bf16* dst;
            if (idx < 8) {
                int s = idx >> 2;
                int rg = idx & 3;
                const __bf16* A = s ? hbf : aggb;
                src = A + (size_t)(nodeBlock + rg * 16 + r4) * DD + k0 + kb;
                dst = &sA[s][rg * 16][0];
            } else {
                int j = idx - 8;
                int g6 = j >> 2;
                int rg = j & 3;
                const __bf16* B = (g6 < 3) ? wih : whh;
                int brow = (g6 % 3) * 256 + colBlock + rg * 16 + r4;
                src = B + (size_t)brow * DD + k0 + kb;
                dst = &sB[g6][rg * 16][0];
            }
            gload_lds16(src, dst);
        }
        __syncthreads();

        bf16x8 aA[2], aH[2];
#pragma unroll
        for (int nf = 0; nf < 2; nf++) {
            aA[nf] = *(const bf16x8*)&sA[0][nodeHalf + nf * 16 + ln][quad * 8];
            aH[nf] = *(const bf16x8*)&sA[1][nodeHalf + nf * 16 + ln][quad * 8];
        }
#pragma unroll
        for (int g = 0; g < 3; g++) {
#pragma unroll
            for (int cc = 0; cc < 2; cc++) {
                bf16x8 bI = *(const bf16x8*)&sB[g][colHalf + cc * 16 + ln][quad * 8];
                bf16x8 bH = *(const bf16x8*)&sB[3 + g][colHalf + cc * 16 + ln][quad * 8];
#pragma unroll
                for (int nf = 0; nf < 2; nf++) {
                    acc[g][nf][cc] = __builtin_amdgcn_mfma_f32_16x16x32_bf16(aA[nf], bI, acc[g][nf][cc], 0, 0, 0);
                    acc[3 + g][nf][cc] = __builtin_amdgcn_mfma_f32_16x16x32_bf16(aH[nf], bH, acc[3 + g][nf][cc], 0, 0, 0);
                }
            }
        }
    }

    // epilogue
#pragma unroll
    for (int nf = 0; nf < 2; nf++) {
#pragma unroll
        for (int r = 0; r < 4; r++) {
            int n = nodeBlock + nodeHalf + nf * 16 + quad * 4 + r;
            if (n >= NN) continue;
#pragma unroll
            for (int cc = 0; cc < 2; cc++) {
                int d = colBlock + colHalf + cc * 16 + ln;
                float ir = acc[0][nf][cc][r] + b_ih[d];
                float iz = acc[1][nf][cc][r] + b_ih[d + 256];
                float in_ = acc[2][nf][cc][r] + b_ih[d + 512];
                float hr = acc[3][nf][cc][r] + b_hh[d];
                float hz = acc[4][nf][cc][r] + b_hh[d + 256];
                float hn = acc[5][nf][cc][r] + b_hh[d + 512];
                float rr = 1.f / (1.f + __expf(-(ir + hr)));
                float zz = 1.f / (1.f + __expf(-(iz + hz)));
                float ax = in_ + rr * hn;
                float e2 = __expf(-2.f * ax);
                float nnv = 2.f / (1.f + e2) - 1.f;
                float hp = hin[(size_t)n * DD + d];
                float o = (1.f - zz) * nnv + zz * hp;
                hout[(size_t)n * DD + d] = o;
                hbfout[(size_t)n * DD + d] = (__bf16)o;
            }
        }
    }
}

// ---------------- launch ----------------

extern "C" void kernel_launch(void* const* d_in, const int* in_sizes, int n_in,
                              void* d_out, int out_size, void* d_ws, size_t ws_size,
                              hipStream_t stream) {
    const float* x = (const float*)d_in[0];
    const int* edge_index = (const int*)d_in[1];
    const float* edge_attr = (const float*)d_in[2];
    const float* weight = (const float*)d_in[3];
    const float* w_ih = (const float*)d_in[4];
    const float* w_hh = (const float*)d_in[5];
    const float* b_ih = (const float*)d_in[6];
    const float* b_hh = (const float*)d_in[7];

    size_t off = 0;
    char* base = (char*)d_ws;
    auto carve = [&](size_t bytes) -> void* {
        void* p = base + off;
        off += (bytes + 255) & ~(size_t)255;
        return p;
    };
    float* hb = (float*)carve((size_t)NPAD * DD * 4);
    __bf16* hbfA = (__bf16*)carve((size_t)NPAD * DD * 2);
    __bf16* hbfB = (__bf16*)carve((size_t)NPAD * DD * 2);
    __bf16* mb = (__bf16*)carve((size_t)NPAD * DD * 2);
    __bf16* aggb = (__bf16*)carve((size_t)NPAD * DD * 2);
    __bf16* wtb = (__bf16*)carve((size_t)LL * DD * DD * 2);
    __bf16* wihb = (__bf16*)carve((size_t)768 * DD * 2);
    __bf16* whhb = (__bf16*)carve((size_t)768 * DD * 2);
    int* deg = (int*)carve((size_t)NN * 4);
    int* row_start = (int*)carve((size_t)(NN + 1) * 4);
    int* cursor = (int*)carve((size_t)NN * 4);
    int* ssrc = (int*)carve((size_t)EE * 4);
    float* sattr = (float*)carve((size_t)EE * 4);
    (void)ws_size;

    // weight prep + h0 + pad hygiene
    transpose_wb_k<<<dim3(8, 8, LL), dim3(32, 8), 0, stream>>>(weight, wtb);
    conv_gruw_k<<<(768 * 256 + 255) / 256, 256, 0, stream>>>(w_ih, w_hh, wihb, whhb);
    conv_x_k<<<(NN * DD + 255) / 256, 256, 0, stream>>>(x, hb, hbfA);
    pad_zero_k<<<((NPAD - NN) * DD + 255) / 256, 256, 0, stream>>>(hbfA, hbfB, mb, aggb);

    // CSR by dst
    zero_deg_k<<<(NN + 255) / 256, 256, 0, stream>>>(deg);
    hist_k<<<(EE + 255) / 256, 256, 0, stream>>>(edge_index + EE, deg);
    scan_k<<<1, 1024, 0, stream>>>(deg, row_start, cursor);
    fill_k<<<(EE + 255) / 256, 256, 0, stream>>>(edge_index, edge_attr, cursor, ssrc, sattr);

    float* hA = hb;
    float* hB = (float*)d_out;
    __bf16* hbfIn = hbfA;
    __bf16* hbfOut = hbfB;
    for (int l = 0; l < LL; l++) {
        gemm_m_k<<<dim3(157, 4), 256, 0, stream>>>(hbfIn, wtb + (size_t)l * DD * DD, mb);
        aggregate_bf_k<<<2500, 256, 0, stream>>>(mb, row_start, ssrc, sattr, aggb);
        gru_mfma_k<<<dim3(157, 4), 256, 0, stream>>>(aggb, hbfIn, hA, wihb, whhb,
                                                     b_ih, b_hh, hB, hbfOut);
        float* t = hA; hA = hB; hB = t;
        __bf16* tb = hbfIn; hbfIn = hbfOut; hbfOut = tb;
    }
    // 5 swaps: final h landed in d_out
}